// Round 1
// baseline (9.717 us; speedup 1.0000x reference)
//
#include <hip/hip_runtime.h>

// Problem constants (from reference)
#define U_    2000
#define NI_   5000
#define NF_   40000
#define FAC_  10
#define B_    2048
#define FPP_  20

// One 64-lane wave per batch row. Lanes 0..19 each compute one gathered
// feature's contribution: K[u,f] * (dot(H[u], G[f]) + F_B[f]); then a full
// 64-lane shuffle reduction; lane 0 adds I_B[item] and stores.
__global__ __launch_bounds__(256) void kgflex_kernel(
    const int*   __restrict__ user,
    const int*   __restrict__ item,
    const float* __restrict__ H,
    const float* __restrict__ G,
    const float* __restrict__ Kmat,
    const float* __restrict__ F_B,
    const float* __restrict__ I_B,
    const int*   __restrict__ C,
    float*       __restrict__ out)
{
    const int tid  = threadIdx.x;
    const int wave = tid >> 6;            // 4 waves per block
    const int lane = tid & 63;
    const int b    = blockIdx.x * 4 + wave;
    if (b >= B_) return;

    const int u  = user[b];
    const int it = item[b];

    // Broadcast load of the user's 10-element factor vector (L1/L2 cached).
    float h[FAC_];
#pragma unroll
    for (int k = 0; k < FAC_; ++k) h[k] = H[(long)u * FAC_ + k];

    float a = 0.0f;
    if (lane < FPP_) {
        const long coff = ((long)u * NI_ + it) * (long)FPP_ + lane;
        const int  f    = C[coff];
        const float* g  = G + (long)f * FAC_;
        float z = 0.0f;
#pragma unroll
        for (int k = 0; k < FAC_; ++k) z = fmaf(h[k], g[k], z);
        a = Kmat[(long)u * NF_ + f] * (z + F_B[f]);
    }

    // 64-lane tree reduction (lanes >= FPP_ contribute 0).
#pragma unroll
    for (int off = 32; off >= 1; off >>= 1)
        a += __shfl_down(a, off, 64);

    if (lane == 0) out[b] = a + I_B[it];
}

extern "C" void kernel_launch(void* const* d_in, const int* in_sizes, int n_in,
                              void* d_out, int out_size, void* d_ws, size_t ws_size,
                              hipStream_t stream) {
    const int*   user = (const int*)  d_in[0];
    const int*   item = (const int*)  d_in[1];
    const float* H    = (const float*)d_in[2];
    const float* G    = (const float*)d_in[3];
    const float* Kmat = (const float*)d_in[4];
    const float* F_B  = (const float*)d_in[5];
    const float* I_B  = (const float*)d_in[6];
    const int*   C    = (const int*)  d_in[7];
    float*       out  = (float*)      d_out;

    const int rows_per_block = 4;                 // 256 threads = 4 waves
    const int grid = (B_ + rows_per_block - 1) / rows_per_block;  // 512
    kgflex_kernel<<<grid, 256, 0, stream>>>(user, item, H, G, Kmat, F_B, I_B, C, out);
}

// Round 2
// 9.705 us; speedup vs baseline: 1.0012x; 1.0012x over previous
//
#include <hip/hip_runtime.h>

// Problem constants (from reference)
#define U_    2000
#define NI_   5000
#define NF_   40000
#define FAC_  10
#define B_    2048
#define FPP_  20

// Two rows per 64-lane wave (32-lane segments). In each half-wave, sub-lanes
// 0..19 each compute one gathered feature's contribution
//   K[u,f] * (dot(H[u], G[f]) + F_B[f]),  f = C[u, item, p]
// then a width-32 shuffle reduction; sub-lane 0 adds I_B[item] and stores.
__global__ __launch_bounds__(256) void kgflex_kernel(
    const int*   __restrict__ user,
    const int*   __restrict__ item,
    const float* __restrict__ H,
    const float* __restrict__ G,
    const float* __restrict__ Kmat,
    const float* __restrict__ F_B,
    const float* __restrict__ I_B,
    const int*   __restrict__ C,
    float*       __restrict__ out)
{
    const int tid  = threadIdx.x;
    const int wave = tid >> 6;            // 4 waves per block
    const int lane = tid & 63;
    const int half = lane >> 5;           // which 32-lane segment
    const int sl   = lane & 31;           // sub-lane within segment
    const int b    = (blockIdx.x * 4 + wave) * 2 + half;   // 8 rows per block

    const int u  = user[b];
    const int it = item[b];

    // User's 10-element factor vector (broadcast within segment, L2-hot).
    float h[FAC_];
#pragma unroll
    for (int k = 0; k < FAC_; ++k) h[k] = H[(long)u * FAC_ + k];

    float a = 0.0f;
    if (sl < FPP_) {
        const long coff = ((long)u * NI_ + it) * (long)FPP_ + sl;
        const int  f    = C[coff];
        const float* g  = G + (long)f * FAC_;
        float z = 0.0f;
#pragma unroll
        for (int k = 0; k < FAC_; ++k) z = fmaf(h[k], g[k], z);
        a = Kmat[(long)u * NF_ + f] * (z + F_B[f]);
    }

    // Width-32 tree reduction (sub-lanes >= FPP_ contribute 0).
#pragma unroll
    for (int off = 16; off >= 1; off >>= 1)
        a += __shfl_down(a, off, 32);

    if (sl == 0) out[b] = a + I_B[it];
}

extern "C" void kernel_launch(void* const* d_in, const int* in_sizes, int n_in,
                              void* d_out, int out_size, void* d_ws, size_t ws_size,
                              hipStream_t stream) {
    const int*   user = (const int*)  d_in[0];
    const int*   item = (const int*)  d_in[1];
    const float* H    = (const float*)d_in[2];
    const float* G    = (const float*)d_in[3];
    const float* Kmat = (const float*)d_in[4];
    const float* F_B  = (const float*)d_in[5];
    const float* I_B  = (const float*)d_in[6];
    const int*   C    = (const int*)  d_in[7];
    float*       out  = (float*)      d_out;

    const int rows_per_block = 8;                  // 4 waves x 2 rows each
    const int grid = B_ / rows_per_block;          // 256
    kgflex_kernel<<<grid, 256, 0, stream>>>(user, item, H, G, Kmat, F_B, I_B, C, out);
}